// Round 13
// baseline (257.298 us; speedup 1.0000x reference)
//
#include <hip/hip_runtime.h>
#include <math.h>
#include <float.h>

#define NN 32
#define EE 512
#define TT 512
#define MM (NN*TT)      // 16384 rows
#define NE 8192         // codes
#define MARGIN 5e-4f

typedef __attribute__((ext_vector_type(8))) short bfrag8;
typedef __attribute__((ext_vector_type(16))) float facc16;

// RTNE fp32 -> bf16
__device__ __forceinline__ ushort bf16_rtne(float v, float* as_f) {
    unsigned u = __float_as_uint(v);
    unsigned r = u + 0x7FFFu + ((u >> 16) & 1u);
    *as_f = __uint_as_float(r & 0xFFFF0000u);
    return (ushort)(r >> 16);
}

// ---------------- fused prep: znorm + enorm + packed codes + counts-zero -----
// blocks 0..63: znorm | 64..95: enorm | 96..2143: pack | 2144..2175: counts=0.
__global__ __launch_bounds__(256) void k_prep_all(
    const float* __restrict__ z, const float* __restrict__ emb,
    float* __restrict__ znorm, float* __restrict__ enorm,
    ushort* __restrict__ ehp, int* __restrict__ counts)
{
    const int blk = blockIdx.x;
    const int tid = threadIdx.x;

    if (blk < 64) {
        int m = blk * 256 + tid;
        int n = m >> 9;
        int t = m & 511;
        const float* base = z + (size_t)n * EE * TT + t;
        float r[4][8];
#pragma unroll
        for (int hh = 0; hh < 4; ++hh)
#pragma unroll
            for (int q = 0; q < 8; ++q) {
                float v = base[(size_t)(hh * 128 + q) * TT];
                r[hh][q] = __fmul_rn(v, v);
            }
        for (int i = 8; i < 128; i += 8) {
#pragma unroll
            for (int hh = 0; hh < 4; ++hh)
#pragma unroll
                for (int q = 0; q < 8; ++q) {
                    float v = base[(size_t)(hh * 128 + i + q) * TT];
                    r[hh][q] = __fadd_rn(r[hh][q], __fmul_rn(v, v));
                }
        }
        float h[4];
#pragma unroll
        for (int hh = 0; hh < 4; ++hh)
            h[hh] = __fadd_rn(
                __fadd_rn(__fadd_rn(r[hh][0], r[hh][1]), __fadd_rn(r[hh][2], r[hh][3])),
                __fadd_rn(__fadd_rn(r[hh][4], r[hh][5]), __fadd_rn(r[hh][6], r[hh][7])));
        znorm[m] = __fadd_rn(__fadd_rn(h[0], h[1]), __fadd_rn(h[2], h[3]));
    } else if (blk < 96) {
        int j = (blk - 64) * 256 + tid;
        const float* base = emb + (size_t)j * EE;
        float r[4][8];
#pragma unroll
        for (int hh = 0; hh < 4; ++hh)
#pragma unroll
            for (int q = 0; q < 8; ++q) {
                float v = base[hh * 128 + q];
                r[hh][q] = __fmul_rn(v, v);
            }
        for (int i = 8; i < 128; i += 8) {
#pragma unroll
            for (int hh = 0; hh < 4; ++hh)
#pragma unroll
                for (int q = 0; q < 8; ++q) {
                    float v = base[hh * 128 + i + q];
                    r[hh][q] = __fadd_rn(r[hh][q], __fmul_rn(v, v));
                }
        }
        float h[4];
#pragma unroll
        for (int hh = 0; hh < 4; ++hh)
            h[hh] = __fadd_rn(
                __fadd_rn(__fadd_rn(r[hh][0], r[hh][1]), __fadd_rn(r[hh][2], r[hh][3])),
                __fadd_rn(__fadd_rn(r[hh][4], r[hh][5]), __fadd_rn(r[hh][6], r[hh][7])));
        enorm[j] = __fadd_rn(__fadd_rn(h[0], h[1]), __fadd_rn(h[2], h[3]));
    } else if (blk < 2144) {
        // ehp byte layout: ((g*32 + ks)*2 + a)*1024 + l31*32 + hh*16
        int c = (blk - 96) * 256 + tid;
        int g    = c >> 12;
        int rem  = c & 4095;
        int ks   = rem >> 7;
        int rem2 = rem & 127;
        int a    = rem2 >> 6;
        int l31  = (rem2 >> 1) & 31;
        int hh   = rem2 & 1;
        int j    = g * 64 + a * 32 + l31;
        int k0   = ks * 16 + hh * 8;
        const float* src = emb + (size_t)j * EE + k0;
        float4 v0 = *(const float4*)src;
        float4 v1 = *(const float4*)(src + 4);
        ushort h[8];
        float f;
        h[0] = bf16_rtne(v0.x, &f); h[1] = bf16_rtne(v0.y, &f);
        h[2] = bf16_rtne(v0.z, &f); h[3] = bf16_rtne(v0.w, &f);
        h[4] = bf16_rtne(v1.x, &f); h[5] = bf16_rtne(v1.y, &f);
        h[6] = bf16_rtne(v1.z, &f); h[7] = bf16_rtne(v1.w, &f);
        *(bfrag8*)((char*)ehp + (size_t)c * 16) = *(const bfrag8*)h;
    } else {
        counts[(blk - 2144) * 256 + tid] = 0;
    }
}

// ---------------- filter: 2 quarters/block, unroll-8 ks, tagged top-2 --------
// Grid 512: qpair = blk&1, rowg = blk>>1. Block handles quarters {qpair, qpair+2}
// (stage z once per 2 quarters). Per-quarter top-2 state -> slot geometry,
// cand layout, tag decode all IDENTICAL to round 11/12 (rescore unchanged).
// Tag in d's low mantissa byte: (jtl<<5)|(JTL<<4)|(g<<2)|qq.
__global__ __launch_bounds__(512, 4) void k_filter(
    const float* __restrict__ z, const ushort* __restrict__ ehp,
    const float* __restrict__ enorm,
    float* __restrict__ candD)
{
    __shared__ char zt[64 * 1024];   // 64 rows x 512 bf16, swizzled: byte ^ ((row&15)<<4)

    const int tid   = threadIdx.x;
    const int blk   = blockIdx.x;
    const int qpair = blk & 1;
    const int rowg  = blk >> 1;
    const int lane  = tid & 63;
    const int wid   = tid >> 6;
    const int l31   = lane & 31;
    const int hh    = lane >> 5;
    const int n     = rowg >> 3;
    const int tt0   = (rowg & 7) * 64;
    const size_t zbase = (size_t)n * EE * TT + tt0;
    const int swz = (l31 & 15) << 4;

    for (int it = tid; it < 8192; it += 512) {
        int mr = it & 63;
        int k0 = (it >> 6) * 4;
        ushort4 h;
        float f;
        h.x = bf16_rtne(z[zbase + (size_t)(k0 + 0) * TT + mr], &f);
        h.y = bf16_rtne(z[zbase + (size_t)(k0 + 1) * TT + mr], &f);
        h.z = bf16_rtne(z[zbase + (size_t)(k0 + 2) * TT + mr], &f);
        h.w = bf16_rtne(z[zbase + (size_t)(k0 + 3) * TT + mr], &f);
        int off = mr * 1024 + ((k0 * 2) ^ ((mr & 15) << 4));
        *(ushort4*)(zt + off) = h;
    }
    __syncthreads();

    float v0[2][2] = { { FLT_MAX, FLT_MAX }, { FLT_MAX, FLT_MAX } };
    float v1[2][2] = { { FLT_MAX, FLT_MAX }, { FLT_MAX, FLT_MAX } };
    const char* brow0 = zt + l31 * 1024;
    const char* brow1 = zt + (32 + l31) * 1024;

#pragma unroll
    for (int qh = 0; qh < 2; ++qh) {
        const int q = qpair + qh * 2;
        for (int jtl = 0; jtl < 4; ++jtl) {
            const int jb = q * 2048 + wid * 256 + jtl * 64;   // global code base
            const int gg = jb >> 6;                           // packed group id
            const char* arp = (const char*)ehp + (size_t)gg * 65536 + l31 * 32 + hh * 16;

            facc16 acc00 = (facc16)(0.0f), acc01 = (facc16)(0.0f);
            facc16 acc10 = (facc16)(0.0f), acc11 = (facc16)(0.0f);

#pragma unroll 8
            for (int ks = 0; ks < 32; ++ks) {
                const int kb = ks * 32 + 16 * hh;
                bfrag8 a0 = *(const bfrag8*)(arp + ks * 2048);          // codes jb..jb+31
                bfrag8 a1 = *(const bfrag8*)(arp + ks * 2048 + 1024);   // codes jb+32..+63
                bfrag8 b0 = *(const bfrag8*)(brow0 + (kb ^ swz));
                bfrag8 b1 = *(const bfrag8*)(brow1 + (kb ^ swz));
                acc00 = __builtin_amdgcn_mfma_f32_32x32x16_bf16(a0, b0, acc00, 0, 0, 0);
                acc01 = __builtin_amdgcn_mfma_f32_32x32x16_bf16(a0, b1, acc01, 0, 0, 0);
                acc10 = __builtin_amdgcn_mfma_f32_32x32x16_bf16(a1, b0, acc10, 0, 0, 0);
                acc11 = __builtin_amdgcn_mfma_f32_32x32x16_bf16(a1, b1, acc11, 0, 0, 0);
            }

            // fold: tagged d = (en - 2*dot) | tag ; branchless top-2 fmin/fmed3
#define FOLDJ(ACCM0, ACCM1, JTL)                                               \
            _Pragma("unroll")                                                  \
            for (int g = 0; g < 4; ++g) {                                      \
                float4 en4 = *(const float4*)&enorm[jb + (JTL) * 32 + 8 * g + 4 * hh]; \
                _Pragma("unroll")                                              \
                for (int qq = 0; qq < 4; ++qq) {                               \
                    float enq = (qq == 0) ? en4.x : (qq == 1) ? en4.y          \
                              : (qq == 2) ? en4.z : en4.w;                     \
                    unsigned tag = (unsigned)((jtl << 5) | ((JTL) << 4) | (g << 2) | qq); \
                    {                                                          \
                        float d = fmaf(-2.0f, ACCM0[4 * g + qq], enq);         \
                        float dt = __uint_as_float((__float_as_uint(d) & 0xFFFFFF00u) | tag); \
                        v1[qh][0] = __builtin_amdgcn_fmed3f(v0[qh][0], v1[qh][0], dt); \
                        v0[qh][0] = fminf(v0[qh][0], dt);                      \
                    }                                                          \
                    {                                                          \
                        float d = fmaf(-2.0f, ACCM1[4 * g + qq], enq);         \
                        float dt = __uint_as_float((__float_as_uint(d) & 0xFFFFFF00u) | tag); \
                        v1[qh][1] = __builtin_amdgcn_fmed3f(v0[qh][1], v1[qh][1], dt); \
                        v0[qh][1] = fminf(v0[qh][1], dt);                      \
                    }                                                          \
                }                                                              \
            }
            FOLDJ(acc00, acc01, 0)
            FOLDJ(acc10, acc11, 1)
#undef FOLDJ
        }
    }

    // dump d-only candidates (j recoverable from tag + slot position)
#pragma unroll
    for (int qh = 0; qh < 2; ++qh) {
        const int q = qpair + qh * 2;
#pragma unroll
        for (int mt = 0; mt < 2; ++mt) {
            int gm = rowg * 64 + mt * 32 + l31;
            size_t base = (size_t)gm * 128 + q * 32 + wid * 4 + hh * 2;
            candD[base]     = v0[qh][mt];
            candD[base + 1] = v1[qh][mt];
        }
    }
}

// decode code index from cand entry index L (0..127) + tagged value
__device__ __forceinline__ int dec_j(int L, float dv) {
    int sq = L >> 5, sw = (L >> 2) & 7, sh = (L >> 1) & 1;
    unsigned tg = __float_as_uint(dv) & 255u;
    return sq * 2048 + sw * 256 + (int)((tg >> 5) * 64 + ((tg >> 4) & 1) * 32
         + ((tg >> 2) & 3) * 8 + (tg & 3)) + sh * 4;
}

// ---------------- rescore: exact fp32 over candidates + flagged-slot rescan --
__global__ __launch_bounds__(512) void k_rescore(
    const float* __restrict__ z, const float* __restrict__ emb,
    const float* __restrict__ znorm, const float* __restrict__ enorm,
    const float* __restrict__ candD,
    int* __restrict__ idx_out)
{
    __shared__ float zf8[8][512];
    const int tid = threadIdx.x;
    const int blk = blockIdx.x;
    const int gm0 = blk * 8;
    const int n   = gm0 >> 9;
    const int t0  = gm0 & 511;
    const size_t zb = (size_t)n * EE * TT + t0;

    for (int i = tid; i < 4096; i += 512) {
        int k = i >> 3, tt = i & 7;
        zf8[tt][k] = z[zb + (size_t)k * TT + tt];
    }
    __syncthreads();

    const int wid = tid >> 6, lane = tid & 63;
    const int gm = gm0 + wid;
    const float* cd = candD + (size_t)gm * 128;
    float d0 = cd[lane];
    float d1 = cd[64 + lane];

    float mn = fminf(d0, d1);
#pragma unroll
    for (int s = 32; s; s >>= 1) mn = fminf(mn, __shfl_xor(mn, s));
    const float th = mn + MARGIN;

    // odd entries are slot 2nd-best: if under th, that slot may have dropped one
    unsigned long long om0 = __ballot((lane & 1) && (d0 <= th));
    unsigned long long om1 = __ballot((lane & 1) && (d1 <= th));
    const float zn = znorm[gm];
    float bd = FLT_MAX;
    int   bj = 0x7fffffff;

    // ---- normal candidates (all lanes cooperate per candidate) ----
#pragma unroll
    for (int half = 0; half < 2; ++half) {
        float dh = half ? d1 : d0;
        unsigned long long mask = __ballot(dh <= th);
        while (mask) {
            int s = __builtin_ctzll(mask);
            mask &= mask - 1;
            float dv = __shfl(dh, s);
            int js = dec_j(half * 64 + s, dv);
            const float* er = emb + (size_t)js * EE;
            float p = 0.f;
#pragma unroll
            for (int qq = 0; qq < 8; ++qq)
                p = fmaf(zf8[wid][qq * 64 + lane], er[qq * 64 + lane], p);
#pragma unroll
            for (int s2 = 1; s2 < 64; s2 <<= 1) p = __fadd_rn(p, __shfl_xor(p, s2));
            float de = fmaf(-2.0f, p, __fadd_rn(zn, enorm[js]));
            if (de < bd || (de == bd && js < bj)) { bd = de; bj = js; }
        }
    }

    // ---- flagged slots: exact rescan of the slot's 128 codes, lane-split ----
#pragma unroll
    for (int half = 0; half < 2; ++half) {
        unsigned long long om = half ? om1 : om0;
        while (om) {
            int s = __builtin_ctzll(om);
            om &= om - 1;
            int L = half * 64 + s;
            int sq = L >> 5, sw = (L >> 2) & 7, sh = (L >> 1) & 1;
            const float4* zr4 = (const float4*)zf8[wid];
#pragma unroll
            for (int c = 0; c < 2; ++c) {
                int i = c * 64 + lane;     // 0..127 within slot
                int js = sq * 2048 + sw * 256 + ((i >> 5) & 3) * 64
                       + ((i >> 4) & 1) * 32 + ((i >> 2) & 3) * 8 + sh * 4 + (i & 3);
                const float4* er4 = (const float4*)(emb + (size_t)js * EE);
                float r0 = 0.f, r1 = 0.f, r2 = 0.f, r3 = 0.f;
#pragma unroll 8
                for (int k = 0; k < 128; k += 4) {
                    float4 a0 = er4[k], a1 = er4[k + 1], a2 = er4[k + 2], a3 = er4[k + 3];
                    float4 b0 = zr4[k], b1 = zr4[k + 1], b2 = zr4[k + 2], b3 = zr4[k + 3];
                    r0 = fmaf(a0.w, b0.w, fmaf(a0.z, b0.z, fmaf(a0.y, b0.y, fmaf(a0.x, b0.x, r0))));
                    r1 = fmaf(a1.w, b1.w, fmaf(a1.z, b1.z, fmaf(a1.y, b1.y, fmaf(a1.x, b1.x, r1))));
                    r2 = fmaf(a2.w, b2.w, fmaf(a2.z, b2.z, fmaf(a2.y, b2.y, fmaf(a2.x, b2.x, r2))));
                    r3 = fmaf(a3.w, b3.w, fmaf(a3.z, b3.z, fmaf(a3.y, b3.y, fmaf(a3.x, b3.x, r3))));
                }
                float p = __fadd_rn(__fadd_rn(r0, r1), __fadd_rn(r2, r3));
                float de = fmaf(-2.0f, p, __fadd_rn(zn, enorm[js]));
                if (de < bd || (de == bd && js < bj)) { bd = de; bj = js; }
            }
        }
    }

    // ---- wave lexicographic reduce ----
#pragma unroll
    for (int s = 1; s < 64; s <<= 1) {
        float dd = __shfl_xor(bd, s);
        int   jj = __shfl_xor(bj, s);
        if (dd < bd || (dd == bd && jj < bj)) { bd = dd; bj = jj; }
    }
    if (lane == 0) idx_out[gm] = bj;
}

// ---------------- epilogue: z_q write + counts + loss partials ---------------
__global__ __launch_bounds__(512) void k_epilogue(
    const float* __restrict__ z, const float* __restrict__ emb,
    const int* __restrict__ idx,
    float* __restrict__ out_zq, int* __restrict__ counts,
    float* __restrict__ loss_part)
{
    __shared__ int bjs[64];
    __shared__ float lred[8];
    const int tid = threadIdx.x;
    const int blk = blockIdx.x;
    const int n   = blk >> 3;
    const int t0  = (blk & 7) * 64;
    const size_t zbase = (size_t)n * EE * TT + t0;

    if (tid < 64) {
        int j = idx[blk * 64 + tid];
        bjs[tid] = j;
        atomicAdd(&counts[j], 1);
    }
    __syncthreads();

    float lacc = 0.f;
    for (int i = tid; i < 64 * EE; i += 512) {
        int e  = i >> 6;
        int rr = i & 63;
        int j  = bjs[rr];
        float q  = emb[(size_t)j * EE + e];
        size_t zi = zbase + (size_t)e * TT + rr;
        float zf = z[zi];
        float diff = __fsub_rn(q, zf);
        out_zq[zi] = __fadd_rn(zf, diff);
        lacc = fmaf(diff, diff, lacc);
    }
#pragma unroll
    for (int off = 32; off; off >>= 1) lacc += __shfl_down(lacc, off);
    if ((tid & 63) == 0) lred[tid >> 6] = lacc;
    __syncthreads();
    if (tid == 0) {
        float s = ((lred[0] + lred[1]) + (lred[2] + lred[3]))
                + ((lred[4] + lred[5]) + (lred[6] + lred[7]));
        loss_part[blk] = s;
    }
}

// ---------------- final scalars ----------------------------------------------
__global__ void k_final(const int* __restrict__ counts,
                        const float* __restrict__ loss_part,
                        float* __restrict__ out)
{
    __shared__ float lw[4], pw[4];
    int tid = threadIdx.x;
    float l = loss_part[tid];
#pragma unroll
    for (int off = 32; off; off >>= 1) l += __shfl_down(l, off);
    if ((tid & 63) == 0) lw[tid >> 6] = l;
    float p = 0.f;
    for (int j = tid; j < NE; j += 256) {
        float e = (float)counts[j] * (1.0f / (float)MM);
        p += e * logf(e + 1e-10f);
    }
#pragma unroll
    for (int off = 32; off; off >>= 1) p += __shfl_down(p, off);
    if ((tid & 63) == 0) pw[tid >> 6] = p;
    __syncthreads();
    if (tid == 0) {
        float ls = (lw[0] + lw[1]) + (lw[2] + lw[3]);
        float m  = ls / (float)((size_t)MM * EE);
        out[(size_t)MM * EE] = m + 0.25f * m;
        float ps = (pw[0] + pw[1]) + (pw[2] + pw[3]);
        out[(size_t)MM * EE + 1] = expf(-ps);
    }
}

extern "C" void kernel_launch(void* const* d_in, const int* in_sizes, int n_in,
                              void* d_out, int out_size, void* d_ws, size_t ws_size,
                              hipStream_t stream) {
    const float* z   = (const float*)d_in[0];
    const float* emb = (const float*)d_in[1];
    float* out = (float*)d_out;

    float* znorm  = (float*)d_ws;                      // 16384 f32
    float* enorm  = znorm + MM;                        // 8192 f32
    int*   counts = (int*)(enorm + NE);                // 8192 i32
    float* parts  = (float*)(counts + NE);             // 256 f32
    int*   idx    = (int*)(parts + 256);               // 16384 i32
    ushort* ehp   = (ushort*)(idx + MM);               // 8 MB packed bf16 codes
    float* candD  = (float*)(ehp + (size_t)NE * EE);   // 16384*128 f32 (8 MB)

    k_prep_all<<<2176, 256, 0, stream>>>(z, emb, znorm, enorm, ehp, counts);
    k_filter<<<512, 512, 0, stream>>>(z, ehp, enorm, candD);
    k_rescore<<<MM / 8, 512, 0, stream>>>(z, emb, znorm, enorm, candD, idx);
    k_epilogue<<<MM / 64, 512, 0, stream>>>(z, emb, idx, out, counts, parts);
    k_final<<<1, 256, 0, stream>>>(counts, parts, out);
}

// Round 14
// 253.088 us; speedup vs baseline: 1.0166x; 1.0166x over previous
//
#include <hip/hip_runtime.h>
#include <math.h>
#include <float.h>

#define NN 32
#define EE 512
#define TT 512
#define MM (NN*TT)      // 16384 rows
#define NE 8192         // codes
#define MARGIN 5e-4f    // d-scale margin (d = zn+en-2dot)
#define MARGIN2 2.5e-4f // dot-scale margin (= MARGIN/2, since d = -2*dot + const)

typedef __attribute__((ext_vector_type(8))) short bfrag8;
typedef __attribute__((ext_vector_type(16))) float facc16;

// RTNE fp32 -> bf16
__device__ __forceinline__ ushort bf16_rtne(float v, float* as_f) {
    unsigned u = __float_as_uint(v);
    unsigned r = u + 0x7FFFu + ((u >> 16) & 1u);
    *as_f = __uint_as_float(r & 0xFFFF0000u);
    return (ushort)(r >> 16);
}

// ---------------- fused prep: znorm + enorm + packed codes + counts-zero -----
// blocks 0..63: znorm | 64..95: enorm | 96..2143: pack | 2144..2175: counts=0.
__global__ __launch_bounds__(256) void k_prep_all(
    const float* __restrict__ z, const float* __restrict__ emb,
    float* __restrict__ znorm, float* __restrict__ enorm,
    ushort* __restrict__ ehp, int* __restrict__ counts)
{
    const int blk = blockIdx.x;
    const int tid = threadIdx.x;

    if (blk < 64) {
        int m = blk * 256 + tid;
        int n = m >> 9;
        int t = m & 511;
        const float* base = z + (size_t)n * EE * TT + t;
        float r[4][8];
#pragma unroll
        for (int hh = 0; hh < 4; ++hh)
#pragma unroll
            for (int q = 0; q < 8; ++q) {
                float v = base[(size_t)(hh * 128 + q) * TT];
                r[hh][q] = __fmul_rn(v, v);
            }
        for (int i = 8; i < 128; i += 8) {
#pragma unroll
            for (int hh = 0; hh < 4; ++hh)
#pragma unroll
                for (int q = 0; q < 8; ++q) {
                    float v = base[(size_t)(hh * 128 + i + q) * TT];
                    r[hh][q] = __fadd_rn(r[hh][q], __fmul_rn(v, v));
                }
        }
        float h[4];
#pragma unroll
        for (int hh = 0; hh < 4; ++hh)
            h[hh] = __fadd_rn(
                __fadd_rn(__fadd_rn(r[hh][0], r[hh][1]), __fadd_rn(r[hh][2], r[hh][3])),
                __fadd_rn(__fadd_rn(r[hh][4], r[hh][5]), __fadd_rn(r[hh][6], r[hh][7])));
        znorm[m] = __fadd_rn(__fadd_rn(h[0], h[1]), __fadd_rn(h[2], h[3]));
    } else if (blk < 96) {
        int j = (blk - 64) * 256 + tid;
        const float* base = emb + (size_t)j * EE;
        float r[4][8];
#pragma unroll
        for (int hh = 0; hh < 4; ++hh)
#pragma unroll
            for (int q = 0; q < 8; ++q) {
                float v = base[hh * 128 + q];
                r[hh][q] = __fmul_rn(v, v);
            }
        for (int i = 8; i < 128; i += 8) {
#pragma unroll
            for (int hh = 0; hh < 4; ++hh)
#pragma unroll
                for (int q = 0; q < 8; ++q) {
                    float v = base[hh * 128 + i + q];
                    r[hh][q] = __fadd_rn(r[hh][q], __fmul_rn(v, v));
                }
        }
        float h[4];
#pragma unroll
        for (int hh = 0; hh < 4; ++hh)
            h[hh] = __fadd_rn(
                __fadd_rn(__fadd_rn(r[hh][0], r[hh][1]), __fadd_rn(r[hh][2], r[hh][3])),
                __fadd_rn(__fadd_rn(r[hh][4], r[hh][5]), __fadd_rn(r[hh][6], r[hh][7])));
        enorm[j] = __fadd_rn(__fadd_rn(h[0], h[1]), __fadd_rn(h[2], h[3]));
    } else if (blk < 2144) {
        // ehp byte layout: ((g*32 + ks)*2 + a)*1024 + l31*32 + hh*16
        int c = (blk - 96) * 256 + tid;
        int g    = c >> 12;
        int rem  = c & 4095;
        int ks   = rem >> 7;
        int rem2 = rem & 127;
        int a    = rem2 >> 6;
        int l31  = (rem2 >> 1) & 31;
        int hh   = rem2 & 1;
        int j    = g * 64 + a * 32 + l31;
        int k0   = ks * 16 + hh * 8;
        const float* src = emb + (size_t)j * EE + k0;
        float4 v0 = *(const float4*)src;
        float4 v1 = *(const float4*)(src + 4);
        ushort h[8];
        float f;
        h[0] = bf16_rtne(v0.x, &f); h[1] = bf16_rtne(v0.y, &f);
        h[2] = bf16_rtne(v0.z, &f); h[3] = bf16_rtne(v0.w, &f);
        h[4] = bf16_rtne(v1.x, &f); h[5] = bf16_rtne(v1.y, &f);
        h[6] = bf16_rtne(v1.z, &f); h[7] = bf16_rtne(v1.w, &f);
        *(bfrag8*)((char*)ehp + (size_t)c * 16) = *(const bfrag8*)h;
    } else {
        counts[(blk - 2144) * 256 + tid] = 0;
    }
}

// ---------------- filter: max-dot top-2 (enorm-free fold), packed A-loads ----
// Grid 512: qpair = blk&1, rowg = blk>>1; block covers quarters {qpair,qpair+2}.
// candD stores TAGGED DOTS (bigger = better); en-spread (<1e-5) absorbed by
// MARGIN (certificate still exact via rescore).  Tag: (jtl<<5)|(JTL<<4)|(g<<2)|qq.
// cand layout: candD[gm*128 + q*32 + wid*4 + hh*2 + e]  (same as rounds 11-13)
__global__ __launch_bounds__(512, 4) void k_filter(
    const float* __restrict__ z, const ushort* __restrict__ ehp,
    float* __restrict__ candD)
{
    __shared__ char zt[64 * 1024];   // 64 rows x 512 bf16, swizzled: byte ^ ((row&15)<<4)

    const int tid   = threadIdx.x;
    const int blk   = blockIdx.x;
    const int qpair = blk & 1;
    const int rowg  = blk >> 1;
    const int lane  = tid & 63;
    const int wid   = tid >> 6;
    const int l31   = lane & 31;
    const int hh    = lane >> 5;
    const int n     = rowg >> 3;
    const int tt0   = (rowg & 7) * 64;
    const size_t zbase = (size_t)n * EE * TT + tt0;
    const int swz = (l31 & 15) << 4;

    for (int it = tid; it < 8192; it += 512) {
        int mr = it & 63;
        int k0 = (it >> 6) * 4;
        ushort4 h;
        float f;
        h.x = bf16_rtne(z[zbase + (size_t)(k0 + 0) * TT + mr], &f);
        h.y = bf16_rtne(z[zbase + (size_t)(k0 + 1) * TT + mr], &f);
        h.z = bf16_rtne(z[zbase + (size_t)(k0 + 2) * TT + mr], &f);
        h.w = bf16_rtne(z[zbase + (size_t)(k0 + 3) * TT + mr], &f);
        int off = mr * 1024 + ((k0 * 2) ^ ((mr & 15) << 4));
        *(ushort4*)(zt + off) = h;
    }
    __syncthreads();

    // top-2 MAX of tagged dot, per quarter x per m-tile
    float v0[2][2] = { { -FLT_MAX, -FLT_MAX }, { -FLT_MAX, -FLT_MAX } };
    float v1[2][2] = { { -FLT_MAX, -FLT_MAX }, { -FLT_MAX, -FLT_MAX } };
    const char* brow0 = zt + l31 * 1024;
    const char* brow1 = zt + (32 + l31) * 1024;

#pragma unroll
    for (int qh = 0; qh < 2; ++qh) {
        const int q = qpair + qh * 2;
        for (int jtl = 0; jtl < 4; ++jtl) {
            const int jb = q * 2048 + wid * 256 + jtl * 64;   // global code base
            const int gg = jb >> 6;                           // packed group id
            const char* arp = (const char*)ehp + (size_t)gg * 65536 + l31 * 32 + hh * 16;

            facc16 acc00 = (facc16)(0.0f), acc01 = (facc16)(0.0f);
            facc16 acc10 = (facc16)(0.0f), acc11 = (facc16)(0.0f);

#pragma unroll 8
            for (int ks = 0; ks < 32; ++ks) {
                const int kb = ks * 32 + 16 * hh;
                bfrag8 a0 = *(const bfrag8*)(arp + ks * 2048);          // codes jb..jb+31
                bfrag8 a1 = *(const bfrag8*)(arp + ks * 2048 + 1024);   // codes jb+32..+63
                bfrag8 b0 = *(const bfrag8*)(brow0 + (kb ^ swz));
                bfrag8 b1 = *(const bfrag8*)(brow1 + (kb ^ swz));
                acc00 = __builtin_amdgcn_mfma_f32_32x32x16_bf16(a0, b0, acc00, 0, 0, 0);
                acc01 = __builtin_amdgcn_mfma_f32_32x32x16_bf16(a0, b1, acc01, 0, 0, 0);
                acc10 = __builtin_amdgcn_mfma_f32_32x32x16_bf16(a1, b0, acc10, 0, 0, 0);
                acc11 = __builtin_amdgcn_mfma_f32_32x32x16_bf16(a1, b1, acc11, 0, 0, 0);
            }

            // fold: tagged dot ; branchless top-2 MAX via fmax/fmed3 (no memory)
#define FOLDJ(ACCM0, ACCM1, JTL)                                               \
            _Pragma("unroll")                                                  \
            for (int g = 0; g < 4; ++g) {                                      \
                _Pragma("unroll")                                              \
                for (int qq = 0; qq < 4; ++qq) {                               \
                    unsigned tag = (unsigned)((jtl << 5) | ((JTL) << 4) | (g << 2) | qq); \
                    {                                                          \
                        float dt = __uint_as_float((__float_as_uint(ACCM0[4 * g + qq]) & 0xFFFFFF00u) | tag); \
                        v1[qh][0] = __builtin_amdgcn_fmed3f(v0[qh][0], v1[qh][0], dt); \
                        v0[qh][0] = fmaxf(v0[qh][0], dt);                      \
                    }                                                          \
                    {                                                          \
                        float dt = __uint_as_float((__float_as_uint(ACCM1[4 * g + qq]) & 0xFFFFFF00u) | tag); \
                        v1[qh][1] = __builtin_amdgcn_fmed3f(v0[qh][1], v1[qh][1], dt); \
                        v0[qh][1] = fmaxf(v0[qh][1], dt);                      \
                    }                                                          \
                }                                                              \
            }
            FOLDJ(acc00, acc01, 0)
            FOLDJ(acc10, acc11, 1)
#undef FOLDJ
        }
    }

    // dump d-only candidates (j recoverable from tag + slot position)
#pragma unroll
    for (int qh = 0; qh < 2; ++qh) {
        const int q = qpair + qh * 2;
#pragma unroll
        for (int mt = 0; mt < 2; ++mt) {
            int gm = rowg * 64 + mt * 32 + l31;
            size_t base = (size_t)gm * 128 + q * 32 + wid * 4 + hh * 2;
            candD[base]     = v0[qh][mt];
            candD[base + 1] = v1[qh][mt];
        }
    }
}

// decode code index from cand entry index L (0..127) + tagged value
__device__ __forceinline__ int dec_j(int L, float dv) {
    int sq = L >> 5, sw = (L >> 2) & 7, sh = (L >> 1) & 1;
    unsigned tg = __float_as_uint(dv) & 255u;
    return sq * 2048 + sw * 256 + (int)((tg >> 5) * 64 + ((tg >> 4) & 1) * 32
         + ((tg >> 2) & 3) * 8 + (tg & 3)) + sh * 4;
}

// ---------------- rescore: exact fp32 over candidates + flagged-slot rescan --
// candD holds tagged DOTS (max better); threshold = mx - MARGIN2 (dot scale).
__global__ __launch_bounds__(512) void k_rescore(
    const float* __restrict__ z, const float* __restrict__ emb,
    const float* __restrict__ znorm, const float* __restrict__ enorm,
    const float* __restrict__ candD,
    int* __restrict__ idx_out)
{
    __shared__ float zf8[8][512];
    const int tid = threadIdx.x;
    const int blk = blockIdx.x;
    const int gm0 = blk * 8;
    const int n   = gm0 >> 9;
    const int t0  = gm0 & 511;
    const size_t zb = (size_t)n * EE * TT + t0;

    for (int i = tid; i < 4096; i += 512) {
        int k = i >> 3, tt = i & 7;
        zf8[tt][k] = z[zb + (size_t)k * TT + tt];
    }
    __syncthreads();

    const int wid = tid >> 6, lane = tid & 63;
    const int gm = gm0 + wid;
    const float* cd = candD + (size_t)gm * 128;
    float d0 = cd[lane];
    float d1 = cd[64 + lane];

    float mx = fmaxf(d0, d1);
#pragma unroll
    for (int s = 32; s; s >>= 1) mx = fmaxf(mx, __shfl_xor(mx, s));
    const float th = mx - MARGIN2;

    // odd entries are slot 2nd-best: if over th, that slot may have dropped one
    unsigned long long om0 = __ballot((lane & 1) && (d0 >= th));
    unsigned long long om1 = __ballot((lane & 1) && (d1 >= th));
    const float zn = znorm[gm];
    float bd = FLT_MAX;
    int   bj = 0x7fffffff;

    // ---- normal candidates (all lanes cooperate per candidate) ----
#pragma unroll
    for (int half = 0; half < 2; ++half) {
        float dh = half ? d1 : d0;
        unsigned long long mask = __ballot(dh >= th);
        while (mask) {
            int s = __builtin_ctzll(mask);
            mask &= mask - 1;
            float dv = __shfl(dh, s);
            int js = dec_j(half * 64 + s, dv);
            const float* er = emb + (size_t)js * EE;
            float p = 0.f;
#pragma unroll
            for (int qq = 0; qq < 8; ++qq)
                p = fmaf(zf8[wid][qq * 64 + lane], er[qq * 64 + lane], p);
#pragma unroll
            for (int s2 = 1; s2 < 64; s2 <<= 1) p = __fadd_rn(p, __shfl_xor(p, s2));
            float de = fmaf(-2.0f, p, __fadd_rn(zn, enorm[js]));
            if (de < bd || (de == bd && js < bj)) { bd = de; bj = js; }
        }
    }

    // ---- flagged slots: exact rescan of the slot's 128 codes, lane-split ----
#pragma unroll
    for (int half = 0; half < 2; ++half) {
        unsigned long long om = half ? om1 : om0;
        while (om) {
            int s = __builtin_ctzll(om);
            om &= om - 1;
            int L = half * 64 + s;
            int sq = L >> 5, sw = (L >> 2) & 7, sh = (L >> 1) & 1;
            const float4* zr4 = (const float4*)zf8[wid];
#pragma unroll
            for (int c = 0; c < 2; ++c) {
                int i = c * 64 + lane;     // 0..127 within slot
                int js = sq * 2048 + sw * 256 + ((i >> 5) & 3) * 64
                       + ((i >> 4) & 1) * 32 + ((i >> 2) & 3) * 8 + sh * 4 + (i & 3);
                const float4* er4 = (const float4*)(emb + (size_t)js * EE);
                float r0 = 0.f, r1 = 0.f, r2 = 0.f, r3 = 0.f;
#pragma unroll 8
                for (int k = 0; k < 128; k += 4) {
                    float4 a0 = er4[k], a1 = er4[k + 1], a2 = er4[k + 2], a3 = er4[k + 3];
                    float4 b0 = zr4[k], b1 = zr4[k + 1], b2 = zr4[k + 2], b3 = zr4[k + 3];
                    r0 = fmaf(a0.w, b0.w, fmaf(a0.z, b0.z, fmaf(a0.y, b0.y, fmaf(a0.x, b0.x, r0))));
                    r1 = fmaf(a1.w, b1.w, fmaf(a1.z, b1.z, fmaf(a1.y, b1.y, fmaf(a1.x, b1.x, r1))));
                    r2 = fmaf(a2.w, b2.w, fmaf(a2.z, b2.z, fmaf(a2.y, b2.y, fmaf(a2.x, b2.x, r2))));
                    r3 = fmaf(a3.w, b3.w, fmaf(a3.z, b3.z, fmaf(a3.y, b3.y, fmaf(a3.x, b3.x, r3))));
                }
                float p = __fadd_rn(__fadd_rn(r0, r1), __fadd_rn(r2, r3));
                float de = fmaf(-2.0f, p, __fadd_rn(zn, enorm[js]));
                if (de < bd || (de == bd && js < bj)) { bd = de; bj = js; }
            }
        }
    }

    // ---- wave lexicographic reduce ----
#pragma unroll
    for (int s = 1; s < 64; s <<= 1) {
        float dd = __shfl_xor(bd, s);
        int   jj = __shfl_xor(bj, s);
        if (dd < bd || (dd == bd && jj < bj)) { bd = dd; bj = jj; }
    }
    if (lane == 0) idx_out[gm] = bj;
}

// ---------------- epilogue: z_q write + counts + loss partials ---------------
__global__ __launch_bounds__(512) void k_epilogue(
    const float* __restrict__ z, const float* __restrict__ emb,
    const int* __restrict__ idx,
    float* __restrict__ out_zq, int* __restrict__ counts,
    float* __restrict__ loss_part)
{
    __shared__ int bjs[64];
    __shared__ float lred[8];
    const int tid = threadIdx.x;
    const int blk = blockIdx.x;
    const int n   = blk >> 3;
    const int t0  = (blk & 7) * 64;
    const size_t zbase = (size_t)n * EE * TT + t0;

    if (tid < 64) {
        int j = idx[blk * 64 + tid];
        bjs[tid] = j;
        atomicAdd(&counts[j], 1);
    }
    __syncthreads();

    float lacc = 0.f;
    for (int i = tid; i < 64 * EE; i += 512) {
        int e  = i >> 6;
        int rr = i & 63;
        int j  = bjs[rr];
        float q  = emb[(size_t)j * EE + e];
        size_t zi = zbase + (size_t)e * TT + rr;
        float zf = z[zi];
        float diff = __fsub_rn(q, zf);
        out_zq[zi] = __fadd_rn(zf, diff);
        lacc = fmaf(diff, diff, lacc);
    }
#pragma unroll
    for (int off = 32; off; off >>= 1) lacc += __shfl_down(lacc, off);
    if ((tid & 63) == 0) lred[tid >> 6] = lacc;
    __syncthreads();
    if (tid == 0) {
        float s = ((lred[0] + lred[1]) + (lred[2] + lred[3]))
                + ((lred[4] + lred[5]) + (lred[6] + lred[7]));
        loss_part[blk] = s;
    }
}

// ---------------- final scalars ----------------------------------------------
__global__ void k_final(const int* __restrict__ counts,
                        const float* __restrict__ loss_part,
                        float* __restrict__ out)
{
    __shared__ float lw[4], pw[4];
    int tid = threadIdx.x;
    float l = loss_part[tid];
#pragma unroll
    for (int off = 32; off; off >>= 1) l += __shfl_down(l, off);
    if ((tid & 63) == 0) lw[tid >> 6] = l;
    float p = 0.f;
    for (int j = tid; j < NE; j += 256) {
        float e = (float)counts[j] * (1.0f / (float)MM);
        p += e * logf(e + 1e-10f);
    }
#pragma unroll
    for (int off = 32; off; off >>= 1) p += __shfl_down(p, off);
    if ((tid & 63) == 0) pw[tid >> 6] = p;
    __syncthreads();
    if (tid == 0) {
        float ls = (lw[0] + lw[1]) + (lw[2] + lw[3]);
        float m  = ls / (float)((size_t)MM * EE);
        out[(size_t)MM * EE] = m + 0.25f * m;
        float ps = (pw[0] + pw[1]) + (pw[2] + pw[3]);
        out[(size_t)MM * EE + 1] = expf(-ps);
    }
}

extern "C" void kernel_launch(void* const* d_in, const int* in_sizes, int n_in,
                              void* d_out, int out_size, void* d_ws, size_t ws_size,
                              hipStream_t stream) {
    const float* z   = (const float*)d_in[0];
    const float* emb = (const float*)d_in[1];
    float* out = (float*)d_out;

    float* znorm  = (float*)d_ws;                      // 16384 f32
    float* enorm  = znorm + MM;                        // 8192 f32
    int*   counts = (int*)(enorm + NE);                // 8192 i32
    float* parts  = (float*)(counts + NE);             // 256 f32
    int*   idx    = (int*)(parts + 256);               // 16384 i32
    ushort* ehp   = (ushort*)(idx + MM);               // 8 MB packed bf16 codes
    float* candD  = (float*)(ehp + (size_t)NE * EE);   // 16384*128 f32 (8 MB)

    k_prep_all<<<2176, 256, 0, stream>>>(z, emb, znorm, enorm, ehp, counts);
    k_filter<<<512, 512, 0, stream>>>(z, ehp, candD);
    k_rescore<<<MM / 8, 512, 0, stream>>>(z, emb, znorm, enorm, candD, idx);
    k_epilogue<<<MM / 64, 512, 0, stream>>>(z, emb, idx, out, counts, parts);
    k_final<<<1, 256, 0, stream>>>(counts, parts, out);
}